// Round 9
// baseline (1582.891 us; speedup 1.0000x reference)
//
#include <hip/hip_runtime.h>
#include <hip/hip_bf16.h>
#include <math.h>
#include <stdint.h>

typedef unsigned short u16;
typedef unsigned int   u32;
typedef __attribute__((ext_vector_type(8))) short bf16x8;
typedef __attribute__((ext_vector_type(4))) float f32x4;

#define EDIM 256
#define HDIM 128
#define TLEN 128
#define NUTT 1024
#define UU   32
#define NBU  4          // utterances per scan block -> 512 blocks, 2 per CU

#define WS_FLAG 0
#define WS_LENS 64
#define WS_TAB  4608
#define WS_COPY 8192
#define WS_OF   18874368LL
#define WS_OB   52428800LL

#define MFMA16(a, b, c) __builtin_amdgcn_mfma_f32_16x16x32_bf16((a), (b), (c), 0, 0, 0)
#define SOUT(u, s, j) ((u) * 1096 + (s) * 136 + (j))

__constant__ int G_SZ[18] = {7680000, 98304, 49152, 384, 384, 98304, 49152, 384, 384,
                             65536, 256, 65536, 65536, 256, 65536, 256, 65536, 256};

__device__ __forceinline__ float b2f(u16 b) {
    u32 u = ((u32)b) << 16; float f; __builtin_memcpy(&f, &u, 4); return f;
}
__device__ __forceinline__ u16 f2b(float f) {   // RNE manual (cold paths)
    u32 u; __builtin_memcpy(&u, &f, 4);
    u32 r = u + 0x7FFFu + ((u >> 16) & 1u);
    return (u16)(r >> 16);
}
__device__ __forceinline__ u16 f2b_hw(float f) {
    __hip_bfloat16 h = __float2bfloat16(f);
    u16 v; __builtin_memcpy(&v, &h, 2); return v;
}
__device__ __forceinline__ float fsigmoid(float x) { return 1.0f / (1.0f + __expf(-x)); }
__device__ __forceinline__ float ftanh(float x) { return 1.0f - 2.0f / (__expf(2.0f * x) + 1.0f); }

// -------------------------------------------------------------------------
// k_detect: dtype flag + pointer table + lens. 256 threads, pipelined scan
// (was: 64 threads, 256 latency-exposed iterations ~ tens of µs).
// -------------------------------------------------------------------------
__global__ __launch_bounds__(256)
void k_detect(void* ws,
              const int* __restrict__ d_ids, const int* __restrict__ utt_len,
              const void* a0, const void* a1, const void* a2, const void* a3,
              const void* a4, const void* a5, const void* a6, const void* a7,
              const void* a8, const void* a9, const void* a10, const void* a11,
              const void* a12, const void* a13, const void* a14, const void* a15,
              const void* a16, const void* a17) {
    __shared__ int scnt[4];
    const int tid = threadIdx.x, lane = tid & 63, wid = tid >> 6;
    const u16* p = (const u16*)a0;
    int cnt = 0;
#pragma unroll 8
    for (int i = tid; i < 16384; i += 256)
        cnt += ((p[i] & 0x7F80) == 0x7F80) ? 1 : 0;
#pragma unroll
    for (int o = 32; o > 0; o >>= 1) cnt += __shfl_down(cnt, o);
    if (lane == 0) scnt[wid] = cnt;
    __syncthreads();
    if (tid == 0) {
        const void* orig[18] = {a0,a1,a2,a3,a4,a5,a6,a7,a8,a9,a10,a11,a12,a13,a14,a15,a16,a17};
        const int flag = (scnt[0] + scnt[1] + scnt[2] + scnt[3] > 0) ? 1 : 0;
        *(int*)((char*)ws + WS_FLAG) = flag;
        const u16** tab = (const u16**)((char*)ws + WS_TAB);
        char* base = (char*)ws + WS_COPY;
        long long cum = 0;
        for (int a = 0; a < 18; ++a) {
            tab[a] = flag ? (const u16*)(base + cum * 2) : (const u16*)orig[a];
            cum += G_SZ[a];
        }
    }
    int* lens = (int*)((char*)ws + WS_LENS);
#pragma unroll 4
    for (int n = tid; n < NUTT; n += 256) {
        int b = n >> 5;
        int u = n & (UU - 1);
        int L = utt_len[d_ids[b] * UU + u];
        lens[n] = min(max(L, 1), TLEN);
    }
}

// -------------------------------------------------------------------------
// k_convert: fp32 -> bf16 copies into ws (early-out if inputs already bf16).
// -------------------------------------------------------------------------
__global__ void k_convert(void* ws,
                          const void* a0, const void* a1, const void* a2, const void* a3,
                          const void* a4, const void* a5, const void* a6, const void* a7,
                          const void* a8, const void* a9, const void* a10, const void* a11,
                          const void* a12, const void* a13, const void* a14, const void* a15,
                          const void* a16, const void* a17) {
    if (*(const int*)((const char*)ws + WS_FLAG) == 0) return;
    const void* orig[18] = {a0,a1,a2,a3,a4,a5,a6,a7,a8,a9,a10,a11,a12,a13,a14,a15,a16,a17};
    u16* base = (u16*)((char*)ws + WS_COPY);
    const int gtid = blockIdx.x * blockDim.x + threadIdx.x;
    const int gs   = gridDim.x * blockDim.x;
    long long cum = 0;
    for (int a = 0; a < 18; ++a) {
        const float4* src = (const float4*)orig[a];
        uint2* dst = (uint2*)(base + cum);
        const int n4 = G_SZ[a] >> 2;
        for (int i = gtid; i < n4; i += gs) {
            float4 v = src[i];
            uint2 pk;
            pk.x = (u32)f2b(v.x) | ((u32)f2b(v.y) << 16);
            pk.y = (u32)f2b(v.z) | ((u32)f2b(v.w) << 16);
            dst[i] = pk;
        }
        cum += G_SZ[a];
    }
}

// -------------------------------------------------------------------------
// k_scan: GRU scan. NBU=4, 512 thr, grid 256x2 = 512 blocks -> 2 blocks/CU
// (two INDEPENDENT barrier domains per CU: when one block drains at its
// per-step barrier, the other fills the SIMDs). MFMA D rows: 16 = 4 utts
// x4 copies; quad q4 holds all 4 utts' rows -> quad q4 processes utt q4,
// 1 gate-unit per lane. 3 weight tiles/wave (144 VGPRs, cap 128 via
// launch_bounds for 4 waves/EU). Emb prefetch via LDS; staged coalesced
// flush every 8 steps.
// -------------------------------------------------------------------------
__global__ __launch_bounds__(512, 4)
void k_scan(const int* __restrict__ x, void* ws) {
    const u16* const* tab = (const u16* const*)((char*)ws + WS_TAB);
    const int dir = blockIdx.y;
    const u16* emb  = tab[0];
    const u16* w_ih = tab[1 + dir * 4];
    const u16* w_hh = tab[2 + dir * 4];
    const u16* b_ih = tab[3 + dir * 4];
    const u16* b_hh = tab[4 + dir * 4];
    u16* outp = (u16*)((char*)ws + (dir ? WS_OB : WS_OF));
    const int* lens = (const int*)((char*)ws + WS_LENS);

    const int n0 = blockIdx.x * NBU;
    __shared__ __align__(16) u16 sh_emb[2][NBU][264];
    __shared__ __align__(16) u16 sh_hi[2][NBU * 136];
    __shared__ __align__(16) u16 sh_lo[2][NBU * 136];
    __shared__ __align__(16) u16 sh_out[2][NBU * 1096];
    __shared__ int sh_tok[NBU * TLEN];
    __shared__ int sh_L[NBU];

    const int tid = threadIdx.x, lane = tid & 63, wvi = tid >> 6;
    const int q4 = lane >> 4, mm = lane & 15;
    const int j = wvi * 16 + mm;       // h-dim owned by this lane
    const int u4 = mm & 3;             // A-row utterance (rows duplicated x4)

    for (int i = tid; i < NBU * 136; i += 512) { sh_hi[0][i] = 0; sh_lo[0][i] = 0; }
    if (tid < NBU * TLEN) {
        const int u = tid >> 7, tt = tid & 127;
        sh_tok[tid] = x[(n0 + u) * TLEN + tt];
    }
    if (tid < NBU) sh_L[tid] = lens[n0 + tid];

    bf16x8 wih[3][8]; bf16x8 whh[3][4];
    float bcr, bcz, bxn, bgn;
#pragma unroll
    for (int n3 = 0; n3 < 3; ++n3) {
        const int g = n3 * HDIM + j;
#pragma unroll
        for (int ks = 0; ks < 8; ++ks)
            wih[n3][ks] = *(const bf16x8*)(w_ih + g * EDIM + ks * 32 + q4 * 8);
#pragma unroll
        for (int ks = 0; ks < 4; ++ks)
            whh[n3][ks] = *(const bf16x8*)(w_hh + g * HDIM + ks * 32 + q4 * 8);
    }
    bcr = b2f(b_ih[j]) + b2f(b_hh[j]);
    bcz = b2f(b_ih[HDIM + j]) + b2f(b_hh[HDIM + j]);
    bxn = b2f(b_ih[2 * HDIM + j]);
    bgn = b2f(b_hh[2 * HDIM + j]);

    float hprev = 0.0f;                // lane's state: utt q4, dim j
    const f32x4 zero4 = {0.f, 0.f, 0.f, 0.f};
    __syncthreads();

    // prefetch lanes: waves 0..1; l2 in 0..127 covers 4 utts x 32 chunks
    const bool pwave = (wvi < 2);
    const int l2 = wvi * 64 + lane;
    const int pf_u = l2 & 3;
    const int pf_c = l2 >> 2;          // 0..31, 16B chunks of the 512B row
    const int pf_L = sh_L[pf_u];

    uint4 pf;
    if (pwave) {
        const int te0 = dir ? (pf_L - 1) : 0;
        const int tok = sh_tok[pf_u * TLEN + te0];
        pf = *(const uint4*)(emb + (size_t)tok * EDIM + pf_c * 8);
        *(uint4*)&sh_emb[0][pf_u][pf_c * 8] = pf;
    }
    __syncthreads();

    for (int t = 0; t < TLEN; ++t) {
        const int cur = t & 1, nxt = cur ^ 1;
        const int obuf = (t >> 3) & 1, slot = t & 7;

        if (pwave && (t + 1 < TLEN)) {
            const int te = dir ? max(pf_L - 2 - t, 0) : (t + 1);
            const int tok = sh_tok[pf_u * TLEN + te];
            pf = *(const uint4*)(emb + (size_t)tok * EDIM + pf_c * 8);
        }

        f32x4 accx[3], accg[3];
        {
            bf16x8 a = *(const bf16x8*)&sh_emb[cur][u4][q4 * 8];
#pragma unroll
            for (int n3 = 0; n3 < 3; ++n3) accx[n3] = MFMA16(a, wih[n3][0], zero4);
        }
#pragma unroll
        for (int ks = 1; ks < 8; ++ks) {
            bf16x8 a = *(const bf16x8*)&sh_emb[cur][u4][ks * 32 + q4 * 8];
#pragma unroll
            for (int n3 = 0; n3 < 3; ++n3) accx[n3] = MFMA16(a, wih[n3][ks], accx[n3]);
        }
        {
            bf16x8 ahi = *(const bf16x8*)(sh_hi[cur] + u4 * 136 + q4 * 8);
            bf16x8 alo = *(const bf16x8*)(sh_lo[cur] + u4 * 136 + q4 * 8);
#pragma unroll
            for (int n3 = 0; n3 < 3; ++n3) {
                accg[n3] = MFMA16(ahi, whh[n3][0], zero4);
                accg[n3] = MFMA16(alo, whh[n3][0], accg[n3]);
            }
        }
#pragma unroll
        for (int ks = 1; ks < 4; ++ks) {
            bf16x8 ahi = *(const bf16x8*)(sh_hi[cur] + u4 * 136 + ks * 32 + q4 * 8);
            bf16x8 alo = *(const bf16x8*)(sh_lo[cur] + u4 * 136 + ks * 32 + q4 * 8);
#pragma unroll
            for (int n3 = 0; n3 < 3; ++n3) {
                accg[n3] = MFMA16(ahi, whh[n3][ks], accg[n3]);
                accg[n3] = MFMA16(alo, whh[n3][ks], accg[n3]);
            }
        }

        // ---- gate phase: 1 unit/lane. Quad q4 holds utt q4's row copy at
        // acc element [q4] (rows q4*4+arr = utt arr; pick arr = q4).
        {
            const int u = q4;
            const float r  = fsigmoid(accx[0][q4] + accg[0][q4] + bcr);
            const float z  = fsigmoid(accx[1][q4] + accg[1][q4] + bcz);
            const float nn = ftanh((accx[2][q4] + bxn) + r * (accg[2][q4] + bgn));
            const float hn = (1.0f - z) * nn + z * hprev;
            hprev = hn;
            const u16 hb = f2b_hw(hn);
            sh_hi[nxt][u * 136 + j] = hb;
            sh_lo[nxt][u * 136 + j] = f2b_hw(hn - b2f(hb));
            sh_out[obuf][SOUT(u, slot, j)] = hb;
        }

        if (pwave && (t + 1 < TLEN))
            *(uint4*)&sh_emb[nxt][pf_u][pf_c * 8] = pf;

        __syncthreads();

        if (slot == 7) {
            // flush 8 steps x 4 utt x 128 cols: 32 rows x 16 parts x 16B
            const int rowIdx = tid >> 4;        // 0..31
            const int part   = tid & 15;        // 0..15
            const int fu = rowIdx >> 3, fs = rowIdx & 7;
            const int tt = (t & ~7) + fs;
            const int tout = dir ? (sh_L[fu] - 1 - tt) : tt;
            if (tout >= 0) {
                uint4 v = *(const uint4*)&sh_out[obuf][SOUT(fu, fs, part * 8)];
                *(uint4*)(outp + ((size_t)(n0 + fu) * TLEN + tout) * HDIM + part * 8) = v;
            }
        }
    }
}

// -------------------------------------------------------------------------
// k_attn: single-pass per-wave online-softmax attention + epilogue.
// -------------------------------------------------------------------------
__global__ __launch_bounds__(256)
void k_attn(void* ws, void* outv) {
    const u16* const* tab = (const u16* const*)((char*)ws + WS_TAB);
    const u16* wq = tab[9];  const u16* bq = tab[10];
    const u16* wk = tab[11];
    const u16* wv = tab[12]; const u16* bv = tab[13];
    const u16* wo = tab[14]; const u16* bo = tab[15];
    const u16* wl = tab[16]; const u16* bl = tab[17];
    const int* lens = (const int*)((char*)ws + WS_LENS);
    const int flag = *(const int*)((const char*)ws + WS_FLAG);

    const int n = blockIdx.x;
    const int L = lens[n];
    const u16* hf = (const u16*)((char*)ws + WS_OF) + (size_t)n * TLEN * HDIM;
    const u16* hb = (const u16*)((char*)ws + WS_OB) + (size_t)n * TLEN * HDIM;

    __shared__ float sh_hl[EDIM];
    __shared__ float sh_v1[EDIM];
    __shared__ float sh_uv[EDIM];
    __shared__ float sh_a[4 * EDIM];
    __shared__ float sh_m[4], sh_l[4];

    const int tid = threadIdx.x, lane = tid & 63, wid = tid >> 6;

    sh_hl[tid] = (tid < HDIM) ? b2f(hf[(size_t)(L - 1) * HDIM + tid])
                              : b2f(hb[(size_t)(L - 1) * HDIM + (tid - HDIM)]);
    __syncthreads();

    {   // q = Wq h_last + bq
        float s0 = b2f(bq[tid]), s1 = 0.0f;
        const u16* wr = wq + tid * EDIM;
#pragma unroll
        for (int ks = 0; ks < 32; ks += 2) {
            bf16x8 w8 = *(const bf16x8*)(wr + ks * 8);
            bf16x8 w9 = *(const bf16x8*)(wr + ks * 8 + 8);
#pragma unroll
            for (int d = 0; d < 8; ++d) {
                s0 += b2f((u16)w8[d]) * sh_hl[ks * 8 + d];
                s1 += b2f((u16)w9[d]) * sh_hl[ks * 8 + 8 + d];
            }
        }
        sh_v1[tid] = s0 + s1;
    }
    __syncthreads();

    {   // uv = Wk^T q
        float s0 = 0.0f, s1 = 0.0f;
        for (int i = 0; i < EDIM; i += 2) {
            s0 += b2f(wk[i * EDIM + tid]) * sh_v1[i];
            s1 += b2f(wk[(i + 1) * EDIM + tid]) * sh_v1[i + 1];
        }
        sh_uv[tid] = s0 + s1;
    }
    __syncthreads();

    {   // single pass: score + online softmax + weighted acc
        const int e0 = lane * 4;
        const float u0 = sh_uv[e0], u1 = sh_uv[e0 + 1];
        const float u2 = sh_uv[e0 + 2], u3 = sh_uv[e0 + 3];
        float m = -1e30f, l = 0.0f;
        float a0 = 0.f, a1 = 0.f, a2 = 0.f, a3 = 0.f;
        for (int t = wid; t < L; t += 4) {
            const u16* src = (lane < 32) ? (hf + (size_t)t * HDIM + lane * 4)
                                         : (hb + (size_t)t * HDIM + (lane - 32) * 4);
            uint2 pv = *(const uint2*)src;
            const float h0 = b2f((u16)(pv.x & 0xFFFF));
            const float h1 = b2f((u16)(pv.x >> 16));
            const float h2 = b2f((u16)(pv.y & 0xFFFF));
            const float h3 = b2f((u16)(pv.y >> 16));
            float p = h0 * u0 + h1 * u1 + h2 * u2 + h3 * u3;
#pragma unroll
            for (int o = 32; o > 0; o >>= 1) p += __shfl_xor(p, o);
            const float s = p * 0.0625f;
            const float mn = fmaxf(m, s);
            const float c = __expf(m - mn);
            const float w = __expf(s - mn);
            l = l * c + w;
            a0 = a0 * c + w * h0;
            a1 = a1 * c + w * h1;
            a2 = a2 * c + w * h2;
            a3 = a3 * c + w * h3;
            m = mn;
        }
        sh_a[wid * EDIM + e0]     = a0;
        sh_a[wid * EDIM + e0 + 1] = a1;
        sh_a[wid * EDIM + e0 + 2] = a2;
        sh_a[wid * EDIM + e0 + 3] = a3;
        if (lane == 0) { sh_m[wid] = m; sh_l[wid] = l; }
    }
    __syncthreads();

    {   // merge 4 waves
        const float m0 = sh_m[0], m1 = sh_m[1], m2 = sh_m[2], m3 = sh_m[3];
        const float M = fmaxf(fmaxf(m0, m1), fmaxf(m2, m3));
        const float c0 = __expf(m0 - M), c1 = __expf(m1 - M);
        const float c2 = __expf(m2 - M), c3 = __expf(m3 - M);
        const float den = c0 * sh_l[0] + c1 * sh_l[1] + c2 * sh_l[2] + c3 * sh_l[3];
        const float num = c0 * sh_a[tid] + c1 * sh_a[EDIM + tid] +
                          c2 * sh_a[2 * EDIM + tid] + c3 * sh_a[3 * EDIM + tid];
        sh_hl[tid] = num / den;
    }
    __syncthreads();

    {   // Wv
        float s0 = b2f(bv[tid]), s1 = 0.0f;
        const u16* wr = wv + tid * EDIM;
#pragma unroll
        for (int ks = 0; ks < 32; ks += 2) {
            bf16x8 w8 = *(const bf16x8*)(wr + ks * 8);
            bf16x8 w9 = *(const bf16x8*)(wr + ks * 8 + 8);
#pragma unroll
            for (int d = 0; d < 8; ++d) {
                s0 += b2f((u16)w8[d]) * sh_hl[ks * 8 + d];
                s1 += b2f((u16)w9[d]) * sh_hl[ks * 8 + 8 + d];
            }
        }
        sh_uv[tid] = s0 + s1;
    }
    __syncthreads();

    {   // Wo
        float s0 = b2f(bo[tid]), s1 = 0.0f;
        const u16* wr = wo + tid * EDIM;
#pragma unroll
        for (int ks = 0; ks < 32; ks += 2) {
            bf16x8 w8 = *(const bf16x8*)(wr + ks * 8);
            bf16x8 w9 = *(const bf16x8*)(wr + ks * 8 + 8);
#pragma unroll
            for (int d = 0; d < 8; ++d) {
                s0 += b2f((u16)w8[d]) * sh_uv[ks * 8 + d];
                s1 += b2f((u16)w9[d]) * sh_uv[ks * 8 + 8 + d];
            }
        }
        sh_v1[tid] = s0 + s1;
    }
    __syncthreads();

    {   // Wl -> out
        float s0 = b2f(bl[tid]), s1 = 0.0f;
        const u16* wr = wl + tid * EDIM;
#pragma unroll
        for (int ks = 0; ks < 32; ks += 2) {
            bf16x8 w8 = *(const bf16x8*)(wr + ks * 8);
            bf16x8 w9 = *(const bf16x8*)(wr + ks * 8 + 8);
#pragma unroll
            for (int d = 0; d < 8; ++d) {
                s0 += b2f((u16)w8[d]) * sh_v1[ks * 8 + d];
                s1 += b2f((u16)w9[d]) * sh_v1[ks * 8 + 8 + d];
            }
        }
        const float s = s0 + s1;
        const size_t oidx = (size_t)n * EDIM + tid;
        if (flag) ((float*)outv)[oidx] = s;
        else      ((u16*)outv)[oidx]   = f2b(s);
    }
}

// -------------------------------------------------------------------------
extern "C" void kernel_launch(void* const* d_in, const int* in_sizes, int n_in,
                              void* d_out, int out_size, void* d_ws, size_t ws_size,
                              hipStream_t stream) {
    const int* x       = (const int*)d_in[0];
    const int* d_ids   = (const int*)d_in[1];
    const int* utt_len = (const int*)d_in[2];
    const void* f_arr[18] = {
        d_in[3],
        d_in[4], d_in[5], d_in[6], d_in[7],
        d_in[8], d_in[9], d_in[10], d_in[11],
        d_in[12], d_in[13],
        d_in[14],
        d_in[16], d_in[17],
        d_in[18], d_in[19],
        d_in[20], d_in[21]
    };

    k_detect<<<1, 256, 0, stream>>>(d_ws, d_ids, utt_len,
        f_arr[0], f_arr[1], f_arr[2], f_arr[3], f_arr[4], f_arr[5], f_arr[6], f_arr[7],
        f_arr[8], f_arr[9], f_arr[10], f_arr[11], f_arr[12], f_arr[13], f_arr[14],
        f_arr[15], f_arr[16], f_arr[17]);

    k_convert<<<1024, 256, 0, stream>>>(d_ws,
        f_arr[0], f_arr[1], f_arr[2], f_arr[3], f_arr[4], f_arr[5], f_arr[6], f_arr[7],
        f_arr[8], f_arr[9], f_arr[10], f_arr[11], f_arr[12], f_arr[13], f_arr[14],
        f_arr[15], f_arr[16], f_arr[17]);

    k_scan<<<dim3(NUTT / NBU, 2), 512, 0, stream>>>(x, d_ws);

    k_attn<<<NUTT, 256, 0, stream>>>(d_ws, d_out);
}

// Round 10
// 399.015 us; speedup vs baseline: 3.9670x; 3.9670x over previous
//
#include <hip/hip_runtime.h>
#include <hip/hip_bf16.h>
#include <math.h>
#include <stdint.h>

typedef unsigned short u16;
typedef unsigned int   u32;
typedef __attribute__((ext_vector_type(8))) short bf16x8;
typedef __attribute__((ext_vector_type(4))) float f32x4;

#define EDIM 256
#define HDIM 128
#define TLEN 128
#define NUTT 1024
#define UU   32
#define NBU  8          // utterances per scan block (256 blocks = 1/CU, forced
                        // by 144 VGPRs of register-resident weights per wave)

#define WS_FLAG 0
#define WS_LENS 64
#define WS_TAB  4608
#define WS_COPY 8192
#define WS_OF   18874368LL
#define WS_OB   52428800LL

#define MFMA16(a, b, c) __builtin_amdgcn_mfma_f32_16x16x32_bf16((a), (b), (c), 0, 0, 0)
#define SOUT(u, s, j) ((u) * 1096 + (s) * 136 + (j))

__constant__ int G_SZ[18] = {7680000, 98304, 49152, 384, 384, 98304, 49152, 384, 384,
                             65536, 256, 65536, 65536, 256, 65536, 256, 65536, 256};

__device__ __forceinline__ float b2f(u16 b) {
    u32 u = ((u32)b) << 16; float f; __builtin_memcpy(&f, &u, 4); return f;
}
__device__ __forceinline__ u16 f2b(float f) {   // RNE manual (cold paths)
    u32 u; __builtin_memcpy(&u, &f, 4);
    u32 r = u + 0x7FFFu + ((u >> 16) & 1u);
    return (u16)(r >> 16);
}
__device__ __forceinline__ u16 f2b_hw(float f) {
    __hip_bfloat16 h = __float2bfloat16(f);
    u16 v; __builtin_memcpy(&v, &h, 2); return v;
}
__device__ __forceinline__ float fsigmoid(float x) { return 1.0f / (1.0f + __expf(-x)); }
__device__ __forceinline__ float ftanh(float x) { return 1.0f - 2.0f / (__expf(2.0f * x) + 1.0f); }

// -------------------------------------------------------------------------
// k_convert: merged detect+convert+lens (one launch instead of two).
// EVERY block computes the dtype flag locally from emb's first 32 KB
// (L2-served, deterministic across blocks). Block 0 additionally writes
// flag/table/lens for the downstream kernels. If flag=1, all blocks
// convert their slice fp32->bf16.
// -------------------------------------------------------------------------
__global__ __launch_bounds__(256)
void k_convert(void* ws,
               const int* __restrict__ d_ids, const int* __restrict__ utt_len,
               const void* a0, const void* a1, const void* a2, const void* a3,
               const void* a4, const void* a5, const void* a6, const void* a7,
               const void* a8, const void* a9, const void* a10, const void* a11,
               const void* a12, const void* a13, const void* a14, const void* a15,
               const void* a16, const void* a17) {
    __shared__ int scnt[4];
    const int tid = threadIdx.x, lane = tid & 63, wid = tid >> 6;
    const u16* p = (const u16*)a0;
    int cnt = 0;
#pragma unroll 8
    for (int i = tid; i < 16384; i += 256)
        cnt += ((p[i] & 0x7F80) == 0x7F80) ? 1 : 0;
#pragma unroll
    for (int o = 32; o > 0; o >>= 1) cnt += __shfl_down(cnt, o);
    if (lane == 0) scnt[wid] = cnt;
    __syncthreads();
    const int flag = (scnt[0] + scnt[1] + scnt[2] + scnt[3] > 0) ? 1 : 0;

    if (blockIdx.x == 0) {
        if (tid == 0) {
            const void* orig[18] = {a0,a1,a2,a3,a4,a5,a6,a7,a8,a9,a10,a11,a12,a13,a14,a15,a16,a17};
            *(int*)((char*)ws + WS_FLAG) = flag;
            const u16** tab = (const u16**)((char*)ws + WS_TAB);
            char* base = (char*)ws + WS_COPY;
            long long cum = 0;
            for (int a = 0; a < 18; ++a) {
                tab[a] = flag ? (const u16*)(base + cum * 2) : (const u16*)orig[a];
                cum += G_SZ[a];
            }
        }
        int* lens = (int*)((char*)ws + WS_LENS);
#pragma unroll 4
        for (int n = tid; n < NUTT; n += 256) {
            int b = n >> 5;
            int u = n & (UU - 1);
            int L = utt_len[d_ids[b] * UU + u];
            lens[n] = min(max(L, 1), TLEN);
        }
    }

    if (flag == 0) return;
    const void* orig[18] = {a0,a1,a2,a3,a4,a5,a6,a7,a8,a9,a10,a11,a12,a13,a14,a15,a16,a17};
    u16* base = (u16*)((char*)ws + WS_COPY);
    const int gtid = blockIdx.x * blockDim.x + tid;
    const int gs   = gridDim.x * blockDim.x;
    long long cum = 0;
    for (int a = 0; a < 18; ++a) {
        const float4* src = (const float4*)orig[a];
        uint2* dst = (uint2*)(base + cum);
        const int n4 = G_SZ[a] >> 2;
        for (int i = gtid; i < n4; i += gs) {
            float4 v = src[i];
            uint2 pk;
            pk.x = (u32)f2b(v.x) | ((u32)f2b(v.y) << 16);
            pk.y = (u32)f2b(v.z) | ((u32)f2b(v.w) << 16);
            dst[i] = pk;
        }
        cum += G_SZ[a];
    }
}

// -------------------------------------------------------------------------
// k_scan: GRU scan (R8-proven config: 231 us). 8 utt/block, 512 thr, 256
// blocks = 1/CU. Register-resident weights (116 VGPR — do NOT cap via
// launch_bounds min-waves: R9 showed the allocator evicts weights and
// FETCH explodes 120x). Zero-vector MFMA chain start; r/z biases combined,
// n-gate separate; HW bf16 cvt; emb prefetch via LDS; padded staging with
// coalesced 8-step flush; single barrier/step.
// -------------------------------------------------------------------------
__global__ __launch_bounds__(512)
void k_scan(const int* __restrict__ x, void* ws) {
    const u16* const* tab = (const u16* const*)((char*)ws + WS_TAB);
    const int dir = blockIdx.y;
    const u16* emb  = tab[0];
    const u16* w_ih = tab[1 + dir * 4];
    const u16* w_hh = tab[2 + dir * 4];
    const u16* b_ih = tab[3 + dir * 4];
    const u16* b_hh = tab[4 + dir * 4];
    u16* outp = (u16*)((char*)ws + (dir ? WS_OB : WS_OF));
    const int* lens = (const int*)((char*)ws + WS_LENS);

    const int n0 = blockIdx.x * NBU;
    __shared__ __align__(16) u16 sh_emb[2][NBU][264];
    __shared__ __align__(16) u16 sh_hi[2][NBU * 136];
    __shared__ __align__(16) u16 sh_lo[2][NBU * 136];
    __shared__ __align__(16) u16 sh_out[2][NBU * 1096];
    __shared__ int sh_tok[NBU * TLEN];
    __shared__ int sh_L[NBU];

    const int tid = threadIdx.x, lane = tid & 63, wvi = tid >> 6;
    const int q4 = lane >> 4, mm = lane & 15;
    const int j = wvi * 16 + mm;
    const int u8 = mm & 7;

    for (int i = tid; i < NBU * 136; i += 512) { sh_hi[0][i] = 0; sh_lo[0][i] = 0; }
    for (int i = tid; i < NBU * TLEN; i += 512) {
        const int u = i >> 7, tt = i & 127;
        sh_tok[i] = x[(n0 + u) * TLEN + tt];
    }
    if (tid < NBU) sh_L[tid] = lens[n0 + tid];

    bf16x8 wih[3][8]; bf16x8 whh[3][4];
    float bcr, bcz, bxn, bgn;
#pragma unroll
    for (int n3 = 0; n3 < 3; ++n3) {
        const int g = n3 * HDIM + j;
#pragma unroll
        for (int ks = 0; ks < 8; ++ks)
            wih[n3][ks] = *(const bf16x8*)(w_ih + g * EDIM + ks * 32 + q4 * 8);
#pragma unroll
        for (int ks = 0; ks < 4; ++ks)
            whh[n3][ks] = *(const bf16x8*)(w_hh + g * HDIM + ks * 32 + q4 * 8);
    }
    bcr = b2f(b_ih[j]) + b2f(b_hh[j]);
    bcz = b2f(b_ih[HDIM + j]) + b2f(b_hh[HDIM + j]);
    bxn = b2f(b_ih[2 * HDIM + j]);
    bgn = b2f(b_hh[2 * HDIM + j]);

    const int arr0 = (q4 & 2);
    float hprev[2] = {0.f, 0.f};
    const f32x4 zero4 = {0.f, 0.f, 0.f, 0.f};
    __syncthreads();

    const bool pwave = (wvi < 4);
    const int pf_u = lane & 7;
    const int pf_c = wvi * 8 + (lane >> 3);
    const int pf_L = sh_L[pf_u];

    uint4 pf;
    if (pwave) {
        const int te0 = dir ? (pf_L - 1) : 0;
        const int tok = sh_tok[pf_u * TLEN + te0];
        pf = *(const uint4*)(emb + (size_t)tok * EDIM + pf_c * 8);
        *(uint4*)&sh_emb[0][pf_u][pf_c * 8] = pf;
    }
    __syncthreads();

    for (int t = 0; t < TLEN; ++t) {
        const int cur = t & 1, nxt = cur ^ 1;
        const int obuf = (t >> 3) & 1, slot = t & 7;

        if (pwave && (t + 1 < TLEN)) {
            const int te = dir ? max(pf_L - 2 - t, 0) : (t + 1);
            const int tok = sh_tok[pf_u * TLEN + te];
            pf = *(const uint4*)(emb + (size_t)tok * EDIM + pf_c * 8);
        }

        f32x4 accx[3], accg[3];
        {
            bf16x8 a = *(const bf16x8*)&sh_emb[cur][u8][q4 * 8];
#pragma unroll
            for (int n3 = 0; n3 < 3; ++n3) accx[n3] = MFMA16(a, wih[n3][0], zero4);
        }
#pragma unroll
        for (int ks = 1; ks < 8; ++ks) {
            bf16x8 a = *(const bf16x8*)&sh_emb[cur][u8][ks * 32 + q4 * 8];
#pragma unroll
            for (int n3 = 0; n3 < 3; ++n3) accx[n3] = MFMA16(a, wih[n3][ks], accx[n3]);
        }
        {
            bf16x8 ahi = *(const bf16x8*)(sh_hi[cur] + u8 * 136 + q4 * 8);
            bf16x8 alo = *(const bf16x8*)(sh_lo[cur] + u8 * 136 + q4 * 8);
#pragma unroll
            for (int n3 = 0; n3 < 3; ++n3) {
                accg[n3] = MFMA16(ahi, whh[n3][0], zero4);
                accg[n3] = MFMA16(alo, whh[n3][0], accg[n3]);
            }
        }
#pragma unroll
        for (int ks = 1; ks < 4; ++ks) {
            bf16x8 ahi = *(const bf16x8*)(sh_hi[cur] + u8 * 136 + ks * 32 + q4 * 8);
            bf16x8 alo = *(const bf16x8*)(sh_lo[cur] + u8 * 136 + ks * 32 + q4 * 8);
#pragma unroll
            for (int n3 = 0; n3 < 3; ++n3) {
                accg[n3] = MFMA16(ahi, whh[n3][ks], accg[n3]);
                accg[n3] = MFMA16(alo, whh[n3][ks], accg[n3]);
            }
        }

#pragma unroll
        for (int rr2 = 0; rr2 < 2; ++rr2) {
            const int arr = rr2 + arr0;
            const int u   = (q4 * 4 + arr) & 7;
            const float r  = fsigmoid(accx[0][arr] + accg[0][arr] + bcr);
            const float z  = fsigmoid(accx[1][arr] + accg[1][arr] + bcz);
            const float nn = ftanh((accx[2][arr] + bxn) + r * (accg[2][arr] + bgn));
            const float hn = (1.0f - z) * nn + z * hprev[rr2];
            hprev[rr2] = hn;
            const u16 hb = f2b_hw(hn);
            sh_hi[nxt][u * 136 + j] = hb;
            sh_lo[nxt][u * 136 + j] = f2b_hw(hn - b2f(hb));
            sh_out[obuf][SOUT(u, slot, j)] = hb;
        }

        if (pwave && (t + 1 < TLEN))
            *(uint4*)&sh_emb[nxt][pf_u][pf_c * 8] = pf;

        __syncthreads();

        if (slot == 7) {
            const int rowIdx = tid >> 3;
            const int part   = tid & 7;
            const int fu = rowIdx >> 3, fs = rowIdx & 7;
            const int tt = (t & ~7) + fs;
            const int tout = dir ? (sh_L[fu] - 1 - tt) : tt;
            if (tout >= 0) {
                const u16* srcp = &sh_out[obuf][SOUT(fu, fs, part * 16)];
                uint4 v0 = *(const uint4*)(srcp);
                uint4 v1 = *(const uint4*)(srcp + 8);
                u16* dstp = outp + ((size_t)(n0 + fu) * TLEN + tout) * HDIM + part * 16;
                *(uint4*)(dstp)     = v0;
                *(uint4*)(dstp + 8) = v1;
            }
        }
    }
}

// -------------------------------------------------------------------------
// k_attn: single-pass per-wave online-softmax attention + epilogue.
// -------------------------------------------------------------------------
__global__ __launch_bounds__(256)
void k_attn(void* ws, void* outv) {
    const u16* const* tab = (const u16* const*)((char*)ws + WS_TAB);
    const u16* wq = tab[9];  const u16* bq = tab[10];
    const u16* wk = tab[11];
    const u16* wv = tab[12]; const u16* bv = tab[13];
    const u16* wo = tab[14]; const u16* bo = tab[15];
    const u16* wl = tab[16]; const u16* bl = tab[17];
    const int* lens = (const int*)((char*)ws + WS_LENS);
    const int flag = *(const int*)((const char*)ws + WS_FLAG);

    const int n = blockIdx.x;
    const int L = lens[n];
    const u16* hf = (const u16*)((char*)ws + WS_OF) + (size_t)n * TLEN * HDIM;
    const u16* hb = (const u16*)((char*)ws + WS_OB) + (size_t)n * TLEN * HDIM;

    __shared__ float sh_hl[EDIM];
    __shared__ float sh_v1[EDIM];
    __shared__ float sh_uv[EDIM];
    __shared__ float sh_a[4 * EDIM];
    __shared__ float sh_m[4], sh_l[4];

    const int tid = threadIdx.x, lane = tid & 63, wid = tid >> 6;

    sh_hl[tid] = (tid < HDIM) ? b2f(hf[(size_t)(L - 1) * HDIM + tid])
                              : b2f(hb[(size_t)(L - 1) * HDIM + (tid - HDIM)]);
    __syncthreads();

    {   // q = Wq h_last + bq
        float s0 = b2f(bq[tid]), s1 = 0.0f;
        const u16* wr = wq + tid * EDIM;
#pragma unroll
        for (int ks = 0; ks < 32; ks += 2) {
            bf16x8 w8 = *(const bf16x8*)(wr + ks * 8);
            bf16x8 w9 = *(const bf16x8*)(wr + ks * 8 + 8);
#pragma unroll
            for (int d = 0; d < 8; ++d) {
                s0 += b2f((u16)w8[d]) * sh_hl[ks * 8 + d];
                s1 += b2f((u16)w9[d]) * sh_hl[ks * 8 + 8 + d];
            }
        }
        sh_v1[tid] = s0 + s1;
    }
    __syncthreads();

    {   // uv = Wk^T q
        float s0 = 0.0f, s1 = 0.0f;
        for (int i = 0; i < EDIM; i += 2) {
            s0 += b2f(wk[i * EDIM + tid]) * sh_v1[i];
            s1 += b2f(wk[(i + 1) * EDIM + tid]) * sh_v1[i + 1];
        }
        sh_uv[tid] = s0 + s1;
    }
    __syncthreads();

    {   // single pass: score + online softmax + weighted acc
        const int e0 = lane * 4;
        const float u0 = sh_uv[e0], u1 = sh_uv[e0 + 1];
        const float u2 = sh_uv[e0 + 2], u3 = sh_uv[e0 + 3];
        float m = -1e30f, l = 0.0f;
        float a0 = 0.f, a1 = 0.f, a2 = 0.f, a3 = 0.f;
        for (int t = wid; t < L; t += 4) {
            const u16* src = (lane < 32) ? (hf + (size_t)t * HDIM + lane * 4)
                                         : (hb + (size_t)t * HDIM + (lane - 32) * 4);
            uint2 pv = *(const uint2*)src;
            const float h0 = b2f((u16)(pv.x & 0xFFFF));
            const float h1 = b2f((u16)(pv.x >> 16));
            const float h2 = b2f((u16)(pv.y & 0xFFFF));
            const float h3 = b2f((u16)(pv.y >> 16));
            float p = h0 * u0 + h1 * u1 + h2 * u2 + h3 * u3;
#pragma unroll
            for (int o = 32; o > 0; o >>= 1) p += __shfl_xor(p, o);
            const float s = p * 0.0625f;
            const float mn = fmaxf(m, s);
            const float c = __expf(m - mn);
            const float w = __expf(s - mn);
            l = l * c + w;
            a0 = a0 * c + w * h0;
            a1 = a1 * c + w * h1;
            a2 = a2 * c + w * h2;
            a3 = a3 * c + w * h3;
            m = mn;
        }
        sh_a[wid * EDIM + e0]     = a0;
        sh_a[wid * EDIM + e0 + 1] = a1;
        sh_a[wid * EDIM + e0 + 2] = a2;
        sh_a[wid * EDIM + e0 + 3] = a3;
        if (lane == 0) { sh_m[wid] = m; sh_l[wid] = l; }
    }
    __syncthreads();

    {   // merge 4 waves
        const float m0 = sh_m[0], m1 = sh_m[1], m2 = sh_m[2], m3 = sh_m[3];
        const float M = fmaxf(fmaxf(m0, m1), fmaxf(m2, m3));
        const float c0 = __expf(m0 - M), c1 = __expf(m1 - M);
        const float c2 = __expf(m2 - M), c3 = __expf(m3 - M);
        const float den = c0 * sh_l[0] + c1 * sh_l[1] + c2 * sh_l[2] + c3 * sh_l[3];
        const float num = c0 * sh_a[tid] + c1 * sh_a[EDIM + tid] +
                          c2 * sh_a[2 * EDIM + tid] + c3 * sh_a[3 * EDIM + tid];
        sh_hl[tid] = num / den;
    }
    __syncthreads();

    {   // Wv
        float s0 = b2f(bv[tid]), s1 = 0.0f;
        const u16* wr = wv + tid * EDIM;
#pragma unroll
        for (int ks = 0; ks < 32; ks += 2) {
            bf16x8 w8 = *(const bf16x8*)(wr + ks * 8);
            bf16x8 w9 = *(const bf16x8*)(wr + ks * 8 + 8);
#pragma unroll
            for (int d = 0; d < 8; ++d) {
                s0 += b2f((u16)w8[d]) * sh_hl[ks * 8 + d];
                s1 += b2f((u16)w9[d]) * sh_hl[ks * 8 + 8 + d];
            }
        }
        sh_uv[tid] = s0 + s1;
    }
    __syncthreads();

    {   // Wo
        float s0 = b2f(bo[tid]), s1 = 0.0f;
        const u16* wr = wo + tid * EDIM;
#pragma unroll
        for (int ks = 0; ks < 32; ks += 2) {
            bf16x8 w8 = *(const bf16x8*)(wr + ks * 8);
            bf16x8 w9 = *(const bf16x8*)(wr + ks * 8 + 8);
#pragma unroll
            for (int d = 0; d < 8; ++d) {
                s0 += b2f((u16)w8[d]) * sh_uv[ks * 8 + d];
                s1 += b2f((u16)w9[d]) * sh_uv[ks * 8 + 8 + d];
            }
        }
        sh_v1[tid] = s0 + s1;
    }
    __syncthreads();

    {   // Wl -> out
        float s0 = b2f(bl[tid]), s1 = 0.0f;
        const u16* wr = wl + tid * EDIM;
#pragma unroll
        for (int ks = 0; ks < 32; ks += 2) {
            bf16x8 w8 = *(const bf16x8*)(wr + ks * 8);
            bf16x8 w9 = *(const bf16x8*)(wr + ks * 8 + 8);
#pragma unroll
            for (int d = 0; d < 8; ++d) {
                s0 += b2f((u16)w8[d]) * sh_v1[ks * 8 + d];
                s1 += b2f((u16)w9[d]) * sh_v1[ks * 8 + 8 + d];
            }
        }
        const float s = s0 + s1;
        const size_t oidx = (size_t)n * EDIM + tid;
        if (flag) ((float*)outv)[oidx] = s;
        else      ((u16*)outv)[oidx]   = f2b(s);
    }
}

// -------------------------------------------------------------------------
extern "C" void kernel_launch(void* const* d_in, const int* in_sizes, int n_in,
                              void* d_out, int out_size, void* d_ws, size_t ws_size,
                              hipStream_t stream) {
    const int* x       = (const int*)d_in[0];
    const int* d_ids   = (const int*)d_in[1];
    const int* utt_len = (const int*)d_in[2];
    const void* f_arr[18] = {
        d_in[3],
        d_in[4], d_in[5], d_in[6], d_in[7],
        d_in[8], d_in[9], d_in[10], d_in[11],
        d_in[12], d_in[13],
        d_in[14],
        d_in[16], d_in[17],
        d_in[18], d_in[19],
        d_in[20], d_in[21]
    };

    k_convert<<<512, 256, 0, stream>>>(d_ws, d_ids, utt_len,
        f_arr[0], f_arr[1], f_arr[2], f_arr[3], f_arr[4], f_arr[5], f_arr[6], f_arr[7],
        f_arr[8], f_arr[9], f_arr[10], f_arr[11], f_arr[12], f_arr[13], f_arr[14],
        f_arr[15], f_arr[16], f_arr[17]);

    k_scan<<<dim3(NUTT / NBU, 2), 512, 0, stream>>>(x, d_ws);

    k_attn<<<NUTT, 256, 0, stream>>>(d_ws, d_out);
}